// Round 3
// baseline (375.038 us; speedup 1.0000x reference)
//
#include <hip/hip_runtime.h>
#include <hip/hip_bf16.h>
#include <stdint.h>

typedef __attribute__((ext_vector_type(4))) float f32x4;
typedef __attribute__((ext_vector_type(8))) short short8;

__device__ __forceinline__ ushort f2b(float f) {
    union { __hip_bfloat16 h; ushort u; } c;
    c.h = __float2bfloat16(f);
    return c.u;
}

#define BARRIER()  asm volatile("s_barrier" ::: "memory")
#define LGKM0()    asm volatile("s_waitcnt lgkmcnt(0)" ::: "memory")

struct U8 { float4 lo, hi; };   // one staging quantum: 8 consecutive fp32

// ---- fused GEMM: C[M][N] = x[M][K] * (dequant W)[N][K]^T + bias -------------
// 256x256 tile, BK=64, 8 waves (2Mx4N), 8-phase pipeline, 2-tile LDS dbuf.
// Staging is reg-based: fp32 global -> cvt bf16 (W: * block scale) -> swizzled
// ds_write_b128. All staging deps are register deps -> compiler emits exact
// counted vmcnt waits; barriers/phase structure proven in previous round.
__global__ __launch_bounds__(512, 2)
void gemm256_fused_kernel(const float* __restrict__ X, const float* __restrict__ W,
                          const float* __restrict__ sinv, const float* __restrict__ bias,
                          float* __restrict__ C, int M, int N, int K, int nbk) {
    __shared__ alignas(16) short sm[2][32768];   // [buf][ A:16384 shorts | B:16384 shorts ]

    const int tid  = threadIdx.x;
    const int lane = tid & 63;
    const int wid  = tid >> 6;
    const int wr   = wid >> 2;          // 0..1  -> 128-row slice of C
    const int wc   = wid & 3;           // 0..3  -> 64-col slice of C
    const int nbn  = N >> 8;

    // XCD-aware bijective swizzle (launcher guarantees gridDim.x % 8 == 0)
    const int nwg = gridDim.x;
    const int swz = (blockIdx.x & 7) * (nwg >> 3) + (blockIdx.x >> 3);
    const int bm  = swz / nbn;
    const int bn  = swz % nbn;
    const int bn2 = bn * 2;

    const float* gA = X + (size_t)bm * 256 * K;
    const float* gB = W + (size_t)bn * 256 * K;

    // staging geometry: unit U = 64 rows x 64 cols; thread covers row
    // U*64 + wid*8 + (lane>>3), global col chunk (lane&7) (8 fp32, linear).
    // LDS col chunk = (lane&7) ^ (lane>>3)  (XOR swizzle, matches read side).
    const int srow = wid * 8 + (lane >> 3);
    const int scl8 = (lane & 7) * 8;
    const int wOff = (wid * 8 + (lane >> 3)) * 64 + ((((lane & 7) ^ (lane >> 3))) << 3);

    auto LOAD_A = [&](int U, int kt) -> U8 {
        const float* p = gA + (size_t)(U * 64 + srow) * K + kt * 64 + scl8;
        U8 r; r.lo = *(const float4*)p; r.hi = *(const float4*)(p + 4); return r;
    };
    auto LOAD_B = [&](int U, int kt) -> U8 {
        const float* p = gB + (size_t)(U * 64 + srow) * K + kt * 64 + scl8;
        U8 r; r.lo = *(const float4*)p; r.hi = *(const float4*)(p + 4); return r;
    };
    auto WRITE_A = [&](int U, int buf, const U8& v) {
        short8 r;
        r[0] = (short)f2b(v.lo.x); r[1] = (short)f2b(v.lo.y);
        r[2] = (short)f2b(v.lo.z); r[3] = (short)f2b(v.lo.w);
        r[4] = (short)f2b(v.hi.x); r[5] = (short)f2b(v.hi.y);
        r[6] = (short)f2b(v.hi.z); r[7] = (short)f2b(v.hi.w);
        *(short8*)&sm[buf][U * 4096 + wOff] = r;
    };
    auto WRITE_B = [&](int U, int kt, int buf, const U8& v) {
        const float s = sinv[(bn2 + (U >> 1)) * nbk + (kt >> 1)];   // uniform scalar
        short8 r;
        r[0] = (short)f2b(v.lo.x * s); r[1] = (short)f2b(v.lo.y * s);
        r[2] = (short)f2b(v.lo.z * s); r[3] = (short)f2b(v.lo.w * s);
        r[4] = (short)f2b(v.hi.x * s); r[5] = (short)f2b(v.hi.y * s);
        r[6] = (short)f2b(v.hi.z * s); r[7] = (short)f2b(v.hi.w * s);
        *(short8*)&sm[buf][16384 + U * 4096 + wOff] = r;
    };

    // fragment reads (swizzled): row*64 + ((kk*32 + (lane>>4)*8) ^ ((lane&7)<<3))
    auto LD_A = [&](const short* Ab, int mh, int kk, short8 (&a)[4]) {
#pragma unroll
        for (int m = 0; m < 4; ++m) {
            int row = wr * 128 + mh * 64 + m * 16 + (lane & 15);
            a[m] = *(const short8*)&Ab[row * 64 + ((kk * 32 + (lane >> 4) * 8) ^ ((lane & 7) << 3))];
        }
    };
    auto LD_B = [&](const short* Bb, int kk, short8 (&b)[4]) {
#pragma unroll
        for (int n = 0; n < 4; ++n) {
            int row = wc * 64 + n * 16 + (lane & 15);
            b[n] = *(const short8*)&Bb[row * 64 + ((kk * 32 + (lane >> 4) * 8) ^ ((lane & 7) << 3))];
        }
    };

    f32x4 acc[8][4] = {};
    const int nkt = K >> 6;
    const int t1c = (nkt > 1) ? 1 : 0;

    // ---- prologue: stage tile0 directly (two half-batches), prime ring ------
    {
        U8 u0 = LOAD_A(0, 0), u1 = LOAD_A(1, 0), u2 = LOAD_A(2, 0), u3 = LOAD_A(3, 0);
        WRITE_A(0, 0, u0); WRITE_A(1, 0, u1); WRITE_A(2, 0, u2); WRITE_A(3, 0, u3);
        u0 = LOAD_B(0, 0); u1 = LOAD_B(1, 0); u2 = LOAD_B(2, 0); u3 = LOAD_B(3, 0);
        WRITE_B(0, 0, 0, u0); WRITE_B(1, 0, 0, u1); WRITE_B(2, 0, 0, u2); WRITE_B(3, 0, 0, u3);
    }
    U8 pB0 = LOAD_B(0, t1c), pB1 = LOAD_B(1, t1c);   // ring head: B01(tile 1)
    LGKM0();
    BARRIER();

    for (int t = 0; t < nkt; ++t) {
        const int b  = t & 1;
        const int tb = b ^ 1;
        const short* Ab = &sm[b][0];
        const short* Bb = &sm[b][16384];
        const int tn  = (t + 1 < nkt) ? t + 1 : nkt - 1;   // clamped: keep flow uniform
        const int tnn = (t + 2 < nkt) ? t + 2 : nkt - 1;

        short8 a0[4], a1[4], bf0[4], bf1[4];

        // ---- P0: kk0, m0-3 ---- issue B23(t+1); write B01(t+1)
        LD_A(Ab, 0, 0, a0);
        LD_B(Bb, 0, bf0);
        U8 qB2 = LOAD_B(2, tn), qB3 = LOAD_B(3, tn);
        WRITE_B(0, tn, tb, pB0); WRITE_B(1, tn, tb, pB1);
        BARRIER();
        __builtin_amdgcn_s_setprio(1);
#pragma unroll
        for (int m = 0; m < 4; ++m)
#pragma unroll
            for (int n = 0; n < 4; ++n)
                acc[m][n] = __builtin_amdgcn_mfma_f32_16x16x32_bf16(a0[m], bf0[n], acc[m][n], 0, 0, 0);
        __builtin_amdgcn_s_setprio(0);
        LGKM0();
        BARRIER();

        // ---- P1: kk0, m4-7 ---- issue A01(t+1); write B23(t+1)
        LD_A(Ab, 1, 0, a1);
        U8 qA0 = LOAD_A(0, tn), qA1 = LOAD_A(1, tn);
        WRITE_B(2, tn, tb, qB2); WRITE_B(3, tn, tb, qB3);
        BARRIER();
        __builtin_amdgcn_s_setprio(1);
#pragma unroll
        for (int m = 0; m < 4; ++m)
#pragma unroll
            for (int n = 0; n < 4; ++n)
                acc[4 + m][n] = __builtin_amdgcn_mfma_f32_16x16x32_bf16(a1[m], bf0[n], acc[4 + m][n], 0, 0, 0);
        __builtin_amdgcn_s_setprio(0);
        LGKM0();
        BARRIER();

        // ---- P2: kk1, m0-3 ---- issue A23(t+1); write A01(t+1)
        LD_A(Ab, 0, 1, a0);
        LD_B(Bb, 1, bf1);
        U8 qA2 = LOAD_A(2, tn), qA3 = LOAD_A(3, tn);
        WRITE_A(0, tb, qA0); WRITE_A(1, tb, qA1);
        BARRIER();
        __builtin_amdgcn_s_setprio(1);
#pragma unroll
        for (int m = 0; m < 4; ++m)
#pragma unroll
            for (int n = 0; n < 4; ++n)
                acc[m][n] = __builtin_amdgcn_mfma_f32_16x16x32_bf16(a0[m], bf1[n], acc[m][n], 0, 0, 0);
        __builtin_amdgcn_s_setprio(0);
        LGKM0();
        BARRIER();

        // ---- P3: kk1, m4-7 ---- issue B01(t+2); write A23(t+1)
        LD_A(Ab, 1, 1, a1);
        pB0 = LOAD_B(0, tnn); pB1 = LOAD_B(1, tnn);
        WRITE_A(2, tb, qA2); WRITE_A(3, tb, qA3);
        BARRIER();
        __builtin_amdgcn_s_setprio(1);
#pragma unroll
        for (int m = 0; m < 4; ++m)
#pragma unroll
            for (int n = 0; n < 4; ++n)
                acc[4 + m][n] = __builtin_amdgcn_mfma_f32_16x16x32_bf16(a1[m], bf1[n], acc[4 + m][n], 0, 0, 0);
        __builtin_amdgcn_s_setprio(0);
        LGKM0();
        BARRIER();
    }

    // ---- epilogue: C = acc + bias (fp32) ----
    const int r0 = bm * 256 + wr * 128 + (lane >> 4) * 4;
    const int c0 = bn * 256 + wc * 64 + (lane & 15);
#pragma unroll
    for (int n = 0; n < 4; ++n) {
        float bv = bias[c0 + n * 16];
#pragma unroll
        for (int m = 0; m < 8; ++m) {
#pragma unroll
            for (int r = 0; r < 4; ++r) {
                C[(size_t)(r0 + m * 16 + r) * N + (c0 + n * 16)] = acc[m][n][r] + bv;
            }
        }
    }
}

// ---- fallback (shape-generic, slow but correct, no workspace) ---------------
__global__ void fallback_gemm(const float* __restrict__ x, const float* __restrict__ w,
                              const float* __restrict__ sinv, const float* __restrict__ bias,
                              float* __restrict__ out, int M, int N, int K) {
    int n = blockIdx.x * 64 + (threadIdx.x & 63);
    int m = blockIdx.y * 4 + (threadIdx.x >> 6);
    if (m >= M || n >= N) return;
    const int nbk = K >> 7;
    float acc = 0.f;
    for (int k = 0; k < K; ++k)
        acc += x[(size_t)m * K + k] * w[(size_t)n * K + k] * sinv[(n >> 7) * nbk + (k >> 7)];
    out[(size_t)m * N + n] = acc + bias[n];
}

extern "C" void kernel_launch(void* const* d_in, const int* in_sizes, int n_in,
                              void* d_out, int out_size, void* d_ws, size_t ws_size,
                              hipStream_t stream) {
    const float* x    = (const float*)d_in[0];
    const float* w    = (const float*)d_in[1];
    const float* sinv = (const float*)d_in[2];
    const float* bias = (const float*)d_in[3];
    float* out        = (float*)d_out;

    const int O = in_sizes[3];                  // 4096
    const int K = in_sizes[1] / O;              // 4096
    const int M = (int)((long)in_sizes[0] / K); // B*S = 4096
    const int N = O;

    const int nwg = (M / 256) * (N / 256);
    const bool ok = (M % 256 == 0) && (N % 256 == 0) && (K % 128 == 0) && (nwg % 8 == 0);
    if (ok) {
        gemm256_fused_kernel<<<dim3(nwg), 512, 0, stream>>>(x, w, sinv, bias, out,
                                                            M, N, K, K >> 7);
    } else {
        dim3 g(N / 64, (M + 3) / 4);
        fallback_gemm<<<g, 256, 0, stream>>>(x, w, sinv, bias, out, M, N, K);
    }
}

// Round 4
// 281.433 us; speedup vs baseline: 1.3326x; 1.3326x over previous
//
#include <hip/hip_runtime.h>
#include <hip/hip_bf16.h>
#include <stdint.h>

typedef __attribute__((ext_vector_type(4))) float f32x4;
typedef __attribute__((ext_vector_type(8))) short short8;

__device__ __forceinline__ ushort f2b(float f) {
    union { __hip_bfloat16 h; ushort u; } c;
    c.h = __float2bfloat16(f);
    return c.u;
}

// async global->LDS, 16B per lane. LDS dest is wave-uniform; HW adds lane*16.
__device__ __forceinline__ void gload_lds16(const void* g, void* lds) {
    __builtin_amdgcn_global_load_lds((const __attribute__((address_space(1))) void*)g,
                                     (__attribute__((address_space(3))) void*)lds,
                                     16, 0, 0);
}

#define BARRIER()  asm volatile("s_barrier" ::: "memory")
#define LGKM0()    asm volatile("s_waitcnt lgkmcnt(0)" ::: "memory")
#define VMCNT2()   asm volatile("s_waitcnt vmcnt(2)" ::: "memory")

// ---- pre-pass: x fp32 -> bf16 (8 elems/thread, one shot) --------------------
__global__ void conv_x_kernel(const float* __restrict__ x, ushort* __restrict__ xb, long n8) {
    long i = (long)blockIdx.x * blockDim.x + threadIdx.x;
    if (i >= n8) return;
    const float4* xv = (const float4*)x;
    float4 v0 = xv[i * 2], v1 = xv[i * 2 + 1];
    short8 r;
    r[0] = (short)f2b(v0.x); r[1] = (short)f2b(v0.y); r[2] = (short)f2b(v0.z); r[3] = (short)f2b(v0.w);
    r[4] = (short)f2b(v1.x); r[5] = (short)f2b(v1.y); r[6] = (short)f2b(v1.z); r[7] = (short)f2b(v1.w);
    *(short8*)&xb[i * 8] = r;
}

// ---- pre-pass: w fp32 * blockscale -> bf16 (row-indexed, div-free) ----------
__global__ void conv_w_kernel(const float* __restrict__ w, const float* __restrict__ sinv,
                              ushort* __restrict__ wb, int K, int nbk) {
    const int o = blockIdx.y;
    const int c = (blockIdx.x * blockDim.x + threadIdx.x) * 8;
    if (c >= K) return;
    const float s = sinv[(o >> 7) * nbk + (c >> 7)];
    const float4* wv = (const float4*)(w + (size_t)o * K + c);
    float4 v0 = wv[0], v1 = wv[1];
    short8 r;
    r[0] = (short)f2b(v0.x * s); r[1] = (short)f2b(v0.y * s); r[2] = (short)f2b(v0.z * s); r[3] = (short)f2b(v0.w * s);
    r[4] = (short)f2b(v1.x * s); r[5] = (short)f2b(v1.y * s); r[6] = (short)f2b(v1.z * s); r[7] = (short)f2b(v1.w * s);
    *(short8*)&wb[(size_t)o * K + c] = r;
}

// ---- main GEMM: 256x256 tile, BK=64, 8 waves (2Mx4N) ------------------------
// 2 K-tiles per loop body (8 phases), even 2-gload/phase stagger, vmcnt(2)
// once per K-tile (never 0), XOR-swizzled LDS via pre-swizzled global source.
__global__ __launch_bounds__(512, 2)
void gemm256_kernel(const ushort* __restrict__ A, const ushort* __restrict__ Bm,
                    const float* __restrict__ bias, float* __restrict__ C,
                    int M, int N, int K) {
    __shared__ alignas(16) short sm[2][32768];   // [buf][ A:16384 shorts | B:16384 shorts ]

    const int tid  = threadIdx.x;
    const int lane = tid & 63;
    const int wid  = tid >> 6;
    const int wr   = wid >> 2;          // 0..1  -> 128-row slice of C
    const int wc   = wid & 3;           // 0..3  -> 64-col slice of C
    const int nbn  = N >> 8;

    // XCD-aware bijective swizzle (launcher guarantees gridDim.x % 8 == 0)
    const int nwg = gridDim.x;
    const int swz = (blockIdx.x & 7) * (nwg >> 3) + (blockIdx.x >> 3);
    const int bm  = swz / nbn;
    const int bn  = swz % nbn;

    const short* gA = (const short*)A + (size_t)bm * 256 * K;
    const short* gB = (const short*)Bm + (size_t)bn * 256 * K;

    // staging: unit U = 64 rows x 64 cols (8KB); thread row U*64+wid*8+(lane>>3),
    // global col chunk pre-swizzled so linear LDS write == XOR-swizzled layout.
    const int srow = wid * 8 + (lane >> 3);
    const int scol = ((lane & 7) ^ (lane >> 3)) << 3;

    auto STAGE_A = [&](int U, int kt, int buf) {
        const short* src = gA + (size_t)(U * 64 + srow) * K + kt * 64 + scol;
        gload_lds16(src, &sm[buf][U * 4096 + wid * 512]);
    };
    auto STAGE_B = [&](int U, int kt, int buf) {
        const short* src = gB + (size_t)(U * 64 + srow) * K + kt * 64 + scol;
        gload_lds16(src, &sm[buf][16384 + U * 4096 + wid * 512]);
    };

    // fragment reads (swizzled): row*64 + ((chunk) ^ ((row&7)<<3))
    auto LD_A = [&](const short* Ab, int mh, int kk, short8 (&a)[4]) {
#pragma unroll
        for (int m = 0; m < 4; ++m) {
            int row = wr * 128 + mh * 64 + m * 16 + (lane & 15);
            a[m] = *(const short8*)&Ab[row * 64 + ((kk * 32 + (lane >> 4) * 8) ^ ((lane & 7) << 3))];
        }
    };
    auto LD_B = [&](const short* Bb, int kk, short8 (&b)[4]) {
#pragma unroll
        for (int n = 0; n < 4; ++n) {
            int row = wc * 64 + n * 16 + (lane & 15);
            b[n] = *(const short8*)&Bb[row * 64 + ((kk * 32 + (lane >> 4) * 8) ^ ((lane & 7) << 3))];
        }
    };

    f32x4 acc[8][4] = {};
    const int nkt = K >> 6;   // even (launcher enforces K % 128 == 0)

    // ---- one K-tile = 4 phases. Staging stagger (all race-checked):
    //  P0: stage B0,B1(t+1)->tb   (tb not read this tile)
    //  P1: stage A2,A3(t+1)->tb
    //  P2: stage B2,B3(t+1)->tb
    //  P3: stage A0,A1(t+2)->b    (b rows 0..127; P3 reads rows 128..255 — disjoint)
    //  vmcnt(2) at end of P3 retires all 8 loads of tile t+1, leaves A0,A1(t+2).
    auto KSTEP = [&](int t) {
        const int b  = t & 1;
        const int tb = b ^ 1;
        const short* Ab = &sm[b][0];
        const short* Bb = &sm[b][16384];
        const int tn  = (t + 1 < nkt) ? t + 1 : nkt - 1;
        const int tnn = (t + 2 < nkt) ? t + 2 : nkt - 1;

        short8 a0[4], a1[4], bf0[4], bf1[4];

        // P0: kk0, m0-3
        LD_A(Ab, 0, 0, a0);
        LD_B(Bb, 0, bf0);
        STAGE_B(0, tn, tb); STAGE_B(1, tn, tb);
        BARRIER();
        LGKM0();
        __builtin_amdgcn_s_setprio(1);
#pragma unroll
        for (int m = 0; m < 4; ++m)
#pragma unroll
            for (int n = 0; n < 4; ++n)
                acc[m][n] = __builtin_amdgcn_mfma_f32_16x16x32_bf16(a0[m], bf0[n], acc[m][n], 0, 0, 0);
        __builtin_amdgcn_s_setprio(0);
        BARRIER();

        // P1: kk0, m4-7
        LD_A(Ab, 1, 0, a1);
        STAGE_A(2, tn, tb); STAGE_A(3, tn, tb);
        BARRIER();
        LGKM0();
        __builtin_amdgcn_s_setprio(1);
#pragma unroll
        for (int m = 0; m < 4; ++m)
#pragma unroll
            for (int n = 0; n < 4; ++n)
                acc[4 + m][n] = __builtin_amdgcn_mfma_f32_16x16x32_bf16(a1[m], bf0[n], acc[4 + m][n], 0, 0, 0);
        __builtin_amdgcn_s_setprio(0);
        BARRIER();

        // P2: kk1, m0-3
        LD_A(Ab, 0, 1, a0);
        LD_B(Bb, 1, bf1);
        STAGE_B(2, tn, tb); STAGE_B(3, tn, tb);
        BARRIER();
        LGKM0();
        __builtin_amdgcn_s_setprio(1);
#pragma unroll
        for (int m = 0; m < 4; ++m)
#pragma unroll
            for (int n = 0; n < 4; ++n)
                acc[m][n] = __builtin_amdgcn_mfma_f32_16x16x32_bf16(a0[m], bf1[n], acc[m][n], 0, 0, 0);
        __builtin_amdgcn_s_setprio(0);
        BARRIER();

        // P3: kk1, m4-7
        LD_A(Ab, 1, 1, a1);
        STAGE_A(0, tnn, b); STAGE_A(1, tnn, b);
        BARRIER();
        LGKM0();
        __builtin_amdgcn_s_setprio(1);
#pragma unroll
        for (int m = 0; m < 4; ++m)
#pragma unroll
            for (int n = 0; n < 4; ++n)
                acc[4 + m][n] = __builtin_amdgcn_mfma_f32_16x16x32_bf16(a1[m], bf1[n], acc[4 + m][n], 0, 0, 0);
        __builtin_amdgcn_s_setprio(0);
        VMCNT2();     // retire tile t+1 fully; leave A0,A1(t+2) in flight
        BARRIER();
    };

    // ---- prologue: tile0 (8 units -> buf0) + A0,A1(tile1 -> buf1) in flight
    {
        STAGE_B(0, 0, 0); STAGE_B(1, 0, 0);
        STAGE_A(2, 0, 0); STAGE_A(3, 0, 0);
        STAGE_B(2, 0, 0); STAGE_B(3, 0, 0);
        STAGE_A(0, 0, 0); STAGE_A(1, 0, 0);
        const int t1 = (nkt > 1) ? 1 : 0;
        STAGE_A(0, t1, 1); STAGE_A(1, t1, 1);
        VMCNT2();
        BARRIER();
    }

    // 2 K-tiles per body: 8 phases visible to the scheduler
    for (int t = 0; t < nkt; t += 2) {
        KSTEP(t);
        KSTEP(t + 1);
    }

    // ---- epilogue: C = acc + bias (fp32) ----
    const int r0 = bm * 256 + wr * 128 + (lane >> 4) * 4;
    const int c0 = bn * 256 + wc * 64 + (lane & 15);
#pragma unroll
    for (int n = 0; n < 4; ++n) {
        float bv = bias[c0 + n * 16];
#pragma unroll
        for (int m = 0; m < 8; ++m) {
#pragma unroll
            for (int r = 0; r < 4; ++r) {
                C[(size_t)(r0 + m * 16 + r) * N + (c0 + n * 16)] = acc[m][n][r] + bv;
            }
        }
    }
}

// ---- fallback (shape-generic, slow but correct) -----------------------------
__global__ void fallback_gemm(const float* __restrict__ x, const float* __restrict__ w,
                              const float* __restrict__ sinv, const float* __restrict__ bias,
                              float* __restrict__ out, int M, int N, int K) {
    int n = blockIdx.x * 64 + (threadIdx.x & 63);
    int m = blockIdx.y * 4 + (threadIdx.x >> 6);
    if (m >= M || n >= N) return;
    const int nbk = K >> 7;
    float acc = 0.f;
    for (int k = 0; k < K; ++k)
        acc += x[(size_t)m * K + k] * w[(size_t)n * K + k] * sinv[(n >> 7) * nbk + (k >> 7)];
    out[(size_t)m * N + n] = acc + bias[n];
}

extern "C" void kernel_launch(void* const* d_in, const int* in_sizes, int n_in,
                              void* d_out, int out_size, void* d_ws, size_t ws_size,
                              hipStream_t stream) {
    const float* x    = (const float*)d_in[0];
    const float* w    = (const float*)d_in[1];
    const float* sinv = (const float*)d_in[2];
    const float* bias = (const float*)d_in[3];
    float* out        = (float*)d_out;

    const int O = in_sizes[3];                  // 4096
    const int K = in_sizes[1] / O;              // 4096
    const int M = (int)((long)in_sizes[0] / K); // B*S = 4096
    const int N = O;

    const size_t need = ((size_t)M * K + (size_t)N * K) * sizeof(ushort);
    const int nwg = (M / 256) * (N / 256);
    const bool ok = ws_size >= need && (M % 256 == 0) && (N % 256 == 0) &&
                    (K % 128 == 0) && (nwg % 8 == 0) && ((long)M * K % 2048 == 0) &&
                    (K % 2048 == 0);
    if (ok) {
        ushort* xb = (ushort*)d_ws;
        ushort* wb = xb + (size_t)M * K;
        long n8 = (long)M * K / 8;
        conv_x_kernel<<<dim3((unsigned)(n8 / 256)), 256, 0, stream>>>(x, xb, n8);
        conv_w_kernel<<<dim3(K / 2048, N), 256, 0, stream>>>(w, sinv, wb, K, K >> 7);
        gemm256_kernel<<<dim3(nwg), 512, 0, stream>>>(xb, wb, bias, out, M, N, K);
    } else {
        dim3 g(N / 64, (M + 3) / 4);
        fallback_gemm<<<g, 256, 0, stream>>>(x, w, sinv, bias, out, M, N, K);
    }
}

// Round 5
// 279.286 us; speedup vs baseline: 1.3428x; 1.0077x over previous
//
#include <hip/hip_runtime.h>
#include <hip/hip_bf16.h>
#include <stdint.h>

typedef __attribute__((ext_vector_type(4))) float f32x4;
typedef __attribute__((ext_vector_type(8))) short short8;

__device__ __forceinline__ ushort f2b(float f) {
    union { __hip_bfloat16 h; ushort u; } c;
    c.h = __float2bfloat16(f);
    return c.u;
}

// async global->LDS, 16B per lane. LDS dest is wave-uniform; HW adds lane*16.
__device__ __forceinline__ void gload_lds16(const void* g, void* lds) {
    __builtin_amdgcn_global_load_lds((const __attribute__((address_space(1))) void*)g,
                                     (__attribute__((address_space(3))) void*)lds,
                                     16, 0, 0);
}

#define BARRIER()  asm volatile("s_barrier" ::: "memory")
#define VMCNT2()   asm volatile("s_waitcnt vmcnt(2)" ::: "memory")

// ---- pre-pass: x fp32 -> bf16 (8 elems/thread, one shot) --------------------
__global__ void conv_x_kernel(const float* __restrict__ x, ushort* __restrict__ xb, long n8) {
    long i = (long)blockIdx.x * blockDim.x + threadIdx.x;
    if (i >= n8) return;
    const float4* xv = (const float4*)x;
    float4 v0 = xv[i * 2], v1 = xv[i * 2 + 1];
    short8 r;
    r[0] = (short)f2b(v0.x); r[1] = (short)f2b(v0.y); r[2] = (short)f2b(v0.z); r[3] = (short)f2b(v0.w);
    r[4] = (short)f2b(v1.x); r[5] = (short)f2b(v1.y); r[6] = (short)f2b(v1.z); r[7] = (short)f2b(v1.w);
    *(short8*)&xb[i * 8] = r;
}

// ---- pre-pass: w fp32 * blockscale -> bf16 (row-indexed, div-free) ----------
__global__ void conv_w_kernel(const float* __restrict__ w, const float* __restrict__ sinv,
                              ushort* __restrict__ wb, int K, int nbk) {
    const int o = blockIdx.y;
    const int c = (blockIdx.x * blockDim.x + threadIdx.x) * 8;
    if (c >= K) return;
    const float s = sinv[(o >> 7) * nbk + (c >> 7)];
    const float4* wv = (const float4*)(w + (size_t)o * K + c);
    float4 v0 = wv[0], v1 = wv[1];
    short8 r;
    r[0] = (short)f2b(v0.x * s); r[1] = (short)f2b(v0.y * s); r[2] = (short)f2b(v0.z * s); r[3] = (short)f2b(v0.w * s);
    r[4] = (short)f2b(v1.x * s); r[5] = (short)f2b(v1.y * s); r[6] = (short)f2b(v1.z * s); r[7] = (short)f2b(v1.w * s);
    *(short8*)&wb[(size_t)o * K + c] = r;
}

// ---- main GEMM: 256x256 tile, BK=64, 8 waves (2Mx4N) ------------------------
// Software-pipelined phases: fragment ds_reads for phase p+1 issue inside
// phase p's MFMA cluster (LDS drain overlaps matrix pipe). One barrier per
// phase. vmcnt(2) once per K-tile (never 0). Staging stagger (race-checked):
//   P0: B0,B1(t+1)->tb   P1: A1,A3(t+1)->tb   P2: B2,B3(t+1)->tb
//   P3: A0,A2(t+2)->b    (P3 reads A-units 1,3 from b -- disjoint)
__global__ __launch_bounds__(512, 2)
void gemm256_kernel(const ushort* __restrict__ A, const ushort* __restrict__ Bm,
                    const float* __restrict__ bias, float* __restrict__ C,
                    int M, int N, int K) {
    __shared__ alignas(16) short sm[2][32768];   // [buf][ A:16384 shorts | B:16384 shorts ]

    const int tid  = threadIdx.x;
    const int lane = tid & 63;
    const int wid  = tid >> 6;
    const int wr   = wid >> 2;          // 0..1  -> 128-row slice of C
    const int wc   = wid & 3;           // 0..3  -> 64-col slice of C
    const int nbn  = N >> 8;

    // XCD-aware bijective swizzle (launcher guarantees gridDim.x % 8 == 0)
    const int nwg = gridDim.x;
    const int swz = (blockIdx.x & 7) * (nwg >> 3) + (blockIdx.x >> 3);
    const int bm  = swz / nbn;
    const int bn  = swz % nbn;

    const short* gA = (const short*)A + (size_t)bm * 256 * K;
    const short* gB = (const short*)Bm + (size_t)bn * 256 * K;

    // staging: unit U = 64 rows x 64 cols (8KB); thread row U*64+wid*8+(lane>>3),
    // global col chunk pre-swizzled so linear LDS write == XOR-swizzled layout.
    const int srow = wid * 8 + (lane >> 3);
    const int scol = ((lane & 7) ^ (lane >> 3)) << 3;

    auto STAGE_A = [&](int U, int kt, int buf) {
        const short* src = gA + (size_t)(U * 64 + srow) * K + kt * 64 + scol;
        gload_lds16(src, &sm[buf][U * 4096 + wid * 512]);
    };
    auto STAGE_B = [&](int U, int kt, int buf) {
        const short* src = gB + (size_t)(U * 64 + srow) * K + kt * 64 + scol;
        gload_lds16(src, &sm[buf][16384 + U * 4096 + wid * 512]);
    };

    // fragment reads (swizzled): row*64 + ((chunk*8) ^ ((row&7)*8))
    auto LD_A = [&](const short* Ab, int mh, int kk, short8 (&a)[4]) {
#pragma unroll
        for (int m = 0; m < 4; ++m) {
            int row = wr * 128 + mh * 64 + m * 16 + (lane & 15);
            a[m] = *(const short8*)&Ab[row * 64 + ((kk * 32 + (lane >> 4) * 8) ^ ((lane & 7) << 3))];
        }
    };
    auto LD_B = [&](const short* Bb, int kk, short8 (&b)[4]) {
#pragma unroll
        for (int n = 0; n < 4; ++n) {
            int row = wc * 64 + n * 16 + (lane & 15);
            b[n] = *(const short8*)&Bb[row * 64 + ((kk * 32 + (lane >> 4) * 8) ^ ((lane & 7) << 3))];
        }
    };

    f32x4 acc[8][4] = {};

    auto MFMA_H = [&](int off, short8 (&af)[4], short8 (&bf)[4], int m0, int m1) {
#pragma unroll
        for (int m = m0; m < m1; ++m)
#pragma unroll
            for (int n = 0; n < 4; ++n)
                acc[off + m][n] = __builtin_amdgcn_mfma_f32_16x16x32_bf16(af[m], bf[n], acc[off + m][n], 0, 0, 0);
    };

    const int nkt = K >> 6;   // >= 2 and even (launcher enforces K % 128 == 0)

    auto KSTEP = [&](int t) {
        const int b  = t & 1;
        const int tb = b ^ 1;
        const short* Ab = &sm[b][0];
        const short* Bb = &sm[b][16384];
        const int tn  = (t + 1 < nkt) ? t + 1 : nkt - 1;   // clamped tail: rewrites same bytes
        const int tnn = (t + 2 < nkt) ? t + 2 : nkt - 1;

        short8 aA[4], aB[4], aC[4], aD[4], bA[4], bB[4];

        // ---- P0: frags (mh0,kk0)x(kk0); embedded read aB(mh1,kk0) ----
        BARRIER();
        LD_A(Ab, 0, 0, aA);
        LD_B(Bb, 0, bA);
        __builtin_amdgcn_s_setprio(1);
        MFMA_H(0, aA, bA, 0, 2);
        LD_A(Ab, 1, 0, aB);
        MFMA_H(0, aA, bA, 2, 4);
        __builtin_amdgcn_s_setprio(0);
        STAGE_B(0, tn, tb); STAGE_B(1, tn, tb);

        // ---- P1: (aB,bA); embedded reads aC(mh0,kk1), bB(kk1) ----
        BARRIER();
        __builtin_amdgcn_s_setprio(1);
        MFMA_H(4, aB, bA, 0, 2);
        LD_A(Ab, 0, 1, aC);
        LD_B(Bb, 1, bB);
        MFMA_H(4, aB, bA, 2, 4);
        __builtin_amdgcn_s_setprio(0);
        STAGE_A(1, tn, tb); STAGE_A(3, tn, tb);

        // ---- P2: (aC,bB); embedded read aD(mh1,kk1) ----
        BARRIER();
        __builtin_amdgcn_s_setprio(1);
        MFMA_H(0, aC, bB, 0, 2);
        LD_A(Ab, 1, 1, aD);
        MFMA_H(0, aC, bB, 2, 4);
        __builtin_amdgcn_s_setprio(0);
        STAGE_B(2, tn, tb); STAGE_B(3, tn, tb);

        // ---- P3: (aD,bB); no embedded reads (next tile's frags need vmcnt) ----
        BARRIER();
        __builtin_amdgcn_s_setprio(1);
        MFMA_H(4, aD, bB, 0, 4);
        __builtin_amdgcn_s_setprio(0);
        STAGE_A(0, tnn, b); STAGE_A(2, tnn, b);
        VMCNT2();     // retire all 8 loads of tile t+1; leave A0,A2(t+2) in flight
    };

    // ---- prologue: tile0 (8 units -> buf0) + A0,A2(tile1 -> buf1) in flight
    {
        STAGE_B(0, 0, 0); STAGE_B(1, 0, 0);
        STAGE_A(1, 0, 0); STAGE_A(3, 0, 0);
        STAGE_B(2, 0, 0); STAGE_B(3, 0, 0);
        STAGE_A(0, 0, 0); STAGE_A(2, 0, 0);
        const int t1 = (nkt > 1) ? 1 : 0;
        STAGE_A(0, t1, 1); STAGE_A(2, t1, 1);
        VMCNT2();
    }

    // 2 K-tiles per body: 8 phases visible to the scheduler
    for (int t = 0; t < nkt; t += 2) {
        KSTEP(t);
        KSTEP(t + 1);
    }

    // ---- epilogue: C = acc + bias (fp32); reads regs only, no barrier needed
    const int r0 = bm * 256 + wr * 128 + (lane >> 4) * 4;
    const int c0 = bn * 256 + wc * 64 + (lane & 15);
#pragma unroll
    for (int n = 0; n < 4; ++n) {
        float bv = bias[c0 + n * 16];
#pragma unroll
        for (int m = 0; m < 8; ++m) {
#pragma unroll
            for (int r = 0; r < 4; ++r) {
                C[(size_t)(r0 + m * 16 + r) * N + (c0 + n * 16)] = acc[m][n][r] + bv;
            }
        }
    }
}

// ---- fallback (shape-generic, slow but correct) -----------------------------
__global__ void fallback_gemm(const float* __restrict__ x, const float* __restrict__ w,
                              const float* __restrict__ sinv, const float* __restrict__ bias,
                              float* __restrict__ out, int M, int N, int K) {
    int n = blockIdx.x * 64 + (threadIdx.x & 63);
    int m = blockIdx.y * 4 + (threadIdx.x >> 6);
    if (m >= M || n >= N) return;
    const int nbk = K >> 7;
    float acc = 0.f;
    for (int k = 0; k < K; ++k)
        acc += x[(size_t)m * K + k] * w[(size_t)n * K + k] * sinv[(n >> 7) * nbk + (k >> 7)];
    out[(size_t)m * N + n] = acc + bias[n];
}

extern "C" void kernel_launch(void* const* d_in, const int* in_sizes, int n_in,
                              void* d_out, int out_size, void* d_ws, size_t ws_size,
                              hipStream_t stream) {
    const float* x    = (const float*)d_in[0];
    const float* w    = (const float*)d_in[1];
    const float* sinv = (const float*)d_in[2];
    const float* bias = (const float*)d_in[3];
    float* out        = (float*)d_out;

    const int O = in_sizes[3];                  // 4096
    const int K = in_sizes[1] / O;              // 4096
    const int M = (int)((long)in_sizes[0] / K); // B*S = 4096
    const int N = O;

    const size_t need = ((size_t)M * K + (size_t)N * K) * sizeof(ushort);
    const int nwg = (M / 256) * (N / 256);
    const bool ok = ws_size >= need && (M % 256 == 0) && (N % 256 == 0) &&
                    (K % 128 == 0) && (nwg % 8 == 0) && ((long)M * K % 2048 == 0) &&
                    (K % 2048 == 0);
    if (ok) {
        ushort* xb = (ushort*)d_ws;
        ushort* wb = xb + (size_t)M * K;
        long n8 = (long)M * K / 8;
        conv_x_kernel<<<dim3((unsigned)(n8 / 256)), 256, 0, stream>>>(x, xb, n8);
        conv_w_kernel<<<dim3(K / 2048, N), 256, 0, stream>>>(w, sinv, wb, K, K >> 7);
        gemm256_kernel<<<dim3(nwg), 512, 0, stream>>>(xb, wb, bias, out, M, N, K);
    } else {
        dim3 g(N / 64, (M + 3) / 4);
        fallback_gemm<<<g, 256, 0, stream>>>(x, w, sinv, bias, out, M, N, K);
    }
}

// Round 9
// 279.169 us; speedup vs baseline: 1.3434x; 1.0004x over previous
//
#include <hip/hip_runtime.h>
#include <hip/hip_bf16.h>
#include <stdint.h>

typedef __attribute__((ext_vector_type(4))) float f32x4;
typedef __attribute__((ext_vector_type(8))) short short8;

__device__ __forceinline__ ushort f2b(float f) {
    union { __hip_bfloat16 h; ushort u; } c;
    c.h = __float2bfloat16(f);
    return c.u;
}

// async global->LDS, 16B per lane. LDS dest is wave-uniform; HW adds lane*16.
__device__ __forceinline__ void gload_lds16(const void* g, void* lds) {
    __builtin_amdgcn_global_load_lds((const __attribute__((address_space(1))) void*)g,
                                     (__attribute__((address_space(3))) void*)lds,
                                     16, 0, 0);
}

#define BARRIER()  asm volatile("s_barrier" ::: "memory")
#define VMCNT0()   asm volatile("s_waitcnt vmcnt(0)" ::: "memory")

// ---- fused pre-pass: x -> bf16 (y==0), w * blockscale -> bf16 (y==1) --------
__global__ void conv_both_kernel(const float* __restrict__ x, ushort* __restrict__ xb, long n8x,
                                 const float* __restrict__ w, const float* __restrict__ sinv,
                                 ushort* __restrict__ wb, int K, int nbk, long n8w) {
    long i = (long)blockIdx.x * blockDim.x + threadIdx.x;
    if (blockIdx.y == 0) {
        if (i >= n8x) return;
        const float4* xv = (const float4*)x;
        float4 v0 = xv[i * 2], v1 = xv[i * 2 + 1];
        short8 r;
        r[0] = (short)f2b(v0.x); r[1] = (short)f2b(v0.y); r[2] = (short)f2b(v0.z); r[3] = (short)f2b(v0.w);
        r[4] = (short)f2b(v1.x); r[5] = (short)f2b(v1.y); r[6] = (short)f2b(v1.z); r[7] = (short)f2b(v1.w);
        *(short8*)&xb[i * 8] = r;
    } else {
        if (i >= n8w) return;
        long e = i * 8;
        int o, c;
        if (K == 4096) { o = (int)(e >> 12); c = (int)(e & 4095); }
        else { o = (int)(e / K); c = (int)(e - (long)o * K); }
        const float s = sinv[(o >> 7) * nbk + (c >> 7)];
        const float4* wv = (const float4*)(w + e);
        float4 v0 = wv[0], v1 = wv[1];
        short8 r;
        r[0] = (short)f2b(v0.x * s); r[1] = (short)f2b(v0.y * s); r[2] = (short)f2b(v0.z * s); r[3] = (short)f2b(v0.w * s);
        r[4] = (short)f2b(v1.x * s); r[5] = (short)f2b(v1.y * s); r[6] = (short)f2b(v1.z * s); r[7] = (short)f2b(v1.w * s);
        *(short8*)&wb[e] = r;
    }
}

// ---- main GEMM: 256x256 tile, BK=64, 8 waves (2Mx4N) ------------------------
// Software-pipelined phases (frag ds_reads for p+1 inside p's MFMA cluster).
// Staging: ALL 8 units of tile t+1 issue at P0/P1 of tile t -> youngest load
// gets 2 full phases of flight; vmcnt(0) at P3-end is then ~free and is the
// exact visibility condition with P0's opening barrier. Buffer tb is never
// read during tile t -> stages into tb are barrier-safe (no t+2 tricks).
__global__ __launch_bounds__(512, 2)
void gemm256_kernel(const ushort* __restrict__ A, const ushort* __restrict__ Bm,
                    const float* __restrict__ bias, float* __restrict__ C,
                    int M, int N, int K) {
    __shared__ alignas(16) short sm[2][32768];   // [buf][ A:16384 shorts | B:16384 shorts ]

    const int tid  = threadIdx.x;
    const int lane = tid & 63;
    const int wid  = tid >> 6;
    const int wr   = wid >> 2;          // 0..1  -> 128-row slice of C
    const int wc   = wid & 3;           // 0..3  -> 64-col slice of C
    const int nbn  = N >> 8;

    // XCD-aware bijective swizzle (launcher guarantees gridDim.x % 8 == 0)
    const int nwg = gridDim.x;
    const int swz = (blockIdx.x & 7) * (nwg >> 3) + (blockIdx.x >> 3);
    const int bm  = swz / nbn;
    const int bn  = swz % nbn;

    const short* gA = (const short*)A + (size_t)bm * 256 * K;
    const short* gB = (const short*)Bm + (size_t)bn * 256 * K;

    // staging: unit U = 64 rows x 64 cols (8KB); thread row U*64+wid*8+(lane>>3),
    // global col chunk pre-swizzled so linear LDS write == XOR-swizzled layout.
    const int srow = wid * 8 + (lane >> 3);
    const int scol = ((lane & 7) ^ (lane >> 3)) << 3;

    auto STAGE_A = [&](int U, int kt, int buf) {
        const short* src = gA + (size_t)(U * 64 + srow) * K + kt * 64 + scol;
        gload_lds16(src, &sm[buf][U * 4096 + wid * 512]);
    };
    auto STAGE_B = [&](int U, int kt, int buf) {
        const short* src = gB + (size_t)(U * 64 + srow) * K + kt * 64 + scol;
        gload_lds16(src, &sm[buf][16384 + U * 4096 + wid * 512]);
    };

    // fragment reads (swizzled): row*64 + ((chunk*8) ^ ((row&7)*8))
    auto LD_A = [&](const short* Ab, int mh, int kk, short8 (&a)[4]) {
#pragma unroll
        for (int m = 0; m < 4; ++m) {
            int row = wr * 128 + mh * 64 + m * 16 + (lane & 15);
            a[m] = *(const short8*)&Ab[row * 64 + ((kk * 32 + (lane >> 4) * 8) ^ ((lane & 7) << 3))];
        }
    };
    auto LD_B = [&](const short* Bb, int kk, short8 (&b)[4]) {
#pragma unroll
        for (int n = 0; n < 4; ++n) {
            int row = wc * 64 + n * 16 + (lane & 15);
            b[n] = *(const short8*)&Bb[row * 64 + ((kk * 32 + (lane >> 4) * 8) ^ ((lane & 7) << 3))];
        }
    };

    f32x4 acc[8][4] = {};

    auto MFMA_H = [&](int off, short8 (&af)[4], short8 (&bf)[4], int m0, int m1) {
#pragma unroll
        for (int m = m0; m < m1; ++m)
#pragma unroll
            for (int n = 0; n < 4; ++n)
                acc[off + m][n] = __builtin_amdgcn_mfma_f32_16x16x32_bf16(af[m], bf[n], acc[off + m][n], 0, 0, 0);
    };

    const int nkt = K >> 6;   // >= 2 and even (launcher enforces K % 128 == 0)

    auto KSTEP = [&](int t) {
        const int b  = t & 1;
        const int tb = b ^ 1;
        const short* Ab = &sm[b][0];
        const short* Bb = &sm[b][16384];
        const int tn = (t + 1 < nkt) ? t + 1 : nkt - 1;   // clamped tail: writes to tb, never read

        short8 aA[4], aB[4], aC[4], aD[4], bA[4], bB[4];

        // ---- P0: (mh0,kk0); embedded read aB(mh1,kk0); stage 4 of t+1 ----
        BARRIER();
        LD_A(Ab, 0, 0, aA);
        LD_B(Bb, 0, bA);
        __builtin_amdgcn_s_setprio(1);
        MFMA_H(0, aA, bA, 0, 2);
        LD_A(Ab, 1, 0, aB);
        MFMA_H(0, aA, bA, 2, 4);
        __builtin_amdgcn_s_setprio(0);
        STAGE_B(0, tn, tb); STAGE_B(1, tn, tb);
        STAGE_A(0, tn, tb); STAGE_A(2, tn, tb);

        // ---- P1: (aB,bA); embedded reads aC(mh0,kk1), bB(kk1); stage 4 of t+1 ----
        BARRIER();
        __builtin_amdgcn_s_setprio(1);
        MFMA_H(4, aB, bA, 0, 2);
        LD_A(Ab, 0, 1, aC);
        LD_B(Bb, 1, bB);
        MFMA_H(4, aB, bA, 2, 4);
        __builtin_amdgcn_s_setprio(0);
        STAGE_A(1, tn, tb); STAGE_A(3, tn, tb);
        STAGE_B(2, tn, tb); STAGE_B(3, tn, tb);

        // ---- P2: (aC,bB); embedded read aD(mh1,kk1) ----
        BARRIER();
        __builtin_amdgcn_s_setprio(1);
        MFMA_H(0, aC, bB, 0, 2);
        LD_A(Ab, 1, 1, aD);
        MFMA_H(0, aC, bB, 2, 4);
        __builtin_amdgcn_s_setprio(0);

        // ---- P3: (aD,bB); drain t+1 loads (issued >=2 phases ago -> ~free) ----
        BARRIER();
        __builtin_amdgcn_s_setprio(1);
        MFMA_H(4, aD, bB, 0, 4);
        __builtin_amdgcn_s_setprio(0);
        VMCNT0();
    };

    // ---- prologue: tile0 -> buf0, drain; loop opens with barrier ----
    {
        STAGE_B(0, 0, 0); STAGE_B(1, 0, 0);
        STAGE_A(0, 0, 0); STAGE_A(2, 0, 0);
        STAGE_A(1, 0, 0); STAGE_A(3, 0, 0);
        STAGE_B(2, 0, 0); STAGE_B(3, 0, 0);
        VMCNT0();
    }

    // 2 K-tiles per body: 8 phases visible to the scheduler
    for (int t = 0; t < nkt; t += 2) {
        KSTEP(t);
        KSTEP(t + 1);
    }

    // ---- epilogue: C = acc + bias (fp32); regs only, no barrier needed ----
    const int r0 = bm * 256 + wr * 128 + (lane >> 4) * 4;
    const int c0 = bn * 256 + wc * 64 + (lane & 15);
#pragma unroll
    for (int n = 0; n < 4; ++n) {
        float bv = bias[c0 + n * 16];
#pragma unroll
        for (int m = 0; m < 8; ++m) {
#pragma unroll
            for (int r = 0; r < 4; ++r) {
                C[(size_t)(r0 + m * 16 + r) * N + (c0 + n * 16)] = acc[m][n][r] + bv;
            }
        }
    }
}

// ---- fallback (shape-generic, slow but correct) -----------------------------
__global__ void fallback_gemm(const float* __restrict__ x, const float* __restrict__ w,
                              const float* __restrict__ sinv, const float* __restrict__ bias,
                              float* __restrict__ out, int M, int N, int K) {
    int n = blockIdx.x * 64 + (threadIdx.x & 63);
    int m = blockIdx.y * 4 + (threadIdx.x >> 6);
    if (m >= M || n >= N) return;
    const int nbk = K >> 7;
    float acc = 0.f;
    for (int k = 0; k < K; ++k)
        acc += x[(size_t)m * K + k] * w[(size_t)n * K + k] * sinv[(n >> 7) * nbk + (k >> 7)];
    out[(size_t)m * N + n] = acc + bias[n];
}

extern "C" void kernel_launch(void* const* d_in, const int* in_sizes, int n_in,
                              void* d_out, int out_size, void* d_ws, size_t ws_size,
                              hipStream_t stream) {
    const float* x    = (const float*)d_in[0];
    const float* w    = (const float*)d_in[1];
    const float* sinv = (const float*)d_in[2];
    const float* bias = (const float*)d_in[3];
    float* out        = (float*)d_out;

    const int O = in_sizes[3];                  // 4096
    const int K = in_sizes[1] / O;              // 4096
    const int M = (int)((long)in_sizes[0] / K); // B*S = 4096
    const int N = O;

    const size_t need = ((size_t)M * K + (size_t)N * K) * sizeof(ushort);
    const int nwg = (M / 256) * (N / 256);
    const bool ok = ws_size >= need && (M % 256 == 0) && (N % 256 == 0) &&
                    (K % 128 == 0) && (nwg % 8 == 0) && ((long)M * K % 2048 == 0) &&
                    (K % 2048 == 0);
    if (ok) {
        ushort* xb = (ushort*)d_ws;
        ushort* wb = xb + (size_t)M * K;
        long n8x = (long)M * K / 8;
        long n8w = (long)N * K / 8;
        long n8m = (n8x > n8w) ? n8x : n8w;
        dim3 cg((unsigned)((n8m + 255) / 256), 2);
        conv_both_kernel<<<cg, 256, 0, stream>>>(x, xb, n8x, w, sinv, wb, K, K >> 7, n8w);
        gemm256_kernel<<<dim3(nwg), 512, 0, stream>>>(xb, wb, bias, out, M, N, K);
    } else {
        dim3 g(N / 64, (M + 3) / 4);
        fallback_gemm<<<g, 256, 0, stream>>>(x, w, sinv, bias, out, M, N, K);
    }
}